// Round 2
// baseline (473.982 us; speedup 1.0000x reference)
//
#include <hip/hip_runtime.h>

// MultiheadFeedForward: x[4,4096,2048] fp32; per-head FFN (H=16, dh=128, ff=512)
//   h = relu(x_h @ W1[h] + b1[h]);  out_h = h @ W2[h] + b2[h]
// All global tensors are FP32 (reference dtype). Compute path: convert to bf16,
// MFMA 16x16x32_bf16, fp32 accumulate, fp32 bias, fp32 output.
// Fused two-GEMM kernel, FF streamed in 4 chunks of 128, h kept in LDS (bf16).

typedef __attribute__((ext_vector_type(8))) short short8;
typedef __attribute__((ext_vector_type(4))) short short4v;
typedef __attribute__((ext_vector_type(4))) float f32x4;

#define NHEADS 16
#define DHEAD  128
#define NFF    512
#define DMODEL 2048
#define NTOK   16384
#define MT     128   // token tile per block
#define FC     128   // ff chunk
#define LPAD   136   // LDS row stride (bf16 elems): 272B = 17*16B -> 2-way (free) bank aliasing

__device__ __forceinline__ short f2bf(float f) {
    unsigned u = __builtin_bit_cast(unsigned, f);
    u += 0x7FFFu + ((u >> 16) & 1u);   // RNE
    return (short)(u >> 16);
}

// Batched 32x32-tiled transpose + fp32->bf16 convert: dst[h][c][r] = bf16(src[h][r][c])
__global__ __launch_bounds__(256) void transpose_k(const float* __restrict__ src,
                                                   short* __restrict__ dst,
                                                   int R, int C) {
    __shared__ short tile[32][33];
    const int h = blockIdx.z;
    const float* s = src + (size_t)h * R * C;
    short* d = dst + (size_t)h * R * C;
    const int c0 = blockIdx.x * 32, r0 = blockIdx.y * 32;
    const int t = threadIdx.x;
    for (int p = 0; p < 4; ++p) {
        int v = p * 256 + t;
        int r = v >> 5, cc = v & 31;
        tile[r][cc] = f2bf(s[(size_t)(r0 + r) * C + (c0 + cc)]);
    }
    __syncthreads();
    for (int p = 0; p < 4; ++p) {
        int v = p * 256 + t;
        int cc = v >> 5, r = v & 31;
        d[(size_t)(c0 + cc) * R + (r0 + r)] = tile[r][cc];
    }
}

// Main fused kernel. Grid: (head, mtile) = (16, 128); block 256 (4 waves).
// GEMM1 computes D1[f][m] = W1T(A) x X(B); GEMM2 computes D2[d][m] = W2T(A) x H(B).
// 16x16x32 bf16 MFMA. A-frag: lane holds A[m'=lane&15][k = quad*8 + j].
// B-frag: lane holds B[k = quad*8 + j][n = lane&15]. C/D: col=lane&15, row=quad*4+reg.
__global__ __launch_bounds__(256, 1) void ffn_main(
        const float* __restrict__ x,    // [NTOK][DMODEL] fp32
        const short* __restrict__ w1t,  // [H][NFF][DHEAD] bf16 (f, d)
        const float* __restrict__ b1,   // [H][NFF] fp32
        const short* __restrict__ w2t,  // [H][DHEAD][NFF] bf16 (d, f)
        const float* __restrict__ b2,   // [H][DHEAD] fp32
        float* __restrict__ out) {      // [NTOK][DMODEL] fp32
    __shared__ short W1s[FC][LPAD];    // [f_local][d]
    __shared__ short W2s[DHEAD][LPAD]; // [d][f_local]
    __shared__ short Hs[MT][LPAD];     // [m][f_local]

    const int h    = blockIdx.x;
    const int m0   = blockIdx.y * MT;
    const int tid  = threadIdx.x;
    const int lane = tid & 63;
    const int wave = tid >> 6;
    const int quad = lane >> 4;
    const int l16  = lane & 15;
    const int wf   = wave >> 1;  // f/d half (0/1) of 128
    const int wm   = wave & 1;   // m half (0/1) of 128

    // X enters GEMM1 as B-operand: lane holds B[k=d][n=m] = x[m][d], contiguous in d.
    // K (=DHEAD=128) does not change across chunks -> load fp32 once, convert to bf16 regs.
    short8 xf[4][4];  // [mi][kk]
    {
        const float* xb = x + (size_t)(m0 + wm * 64) * DMODEL + h * DHEAD;
        for (int mi = 0; mi < 4; ++mi)
            for (int kk = 0; kk < 4; ++kk) {
                const float* p = xb + (size_t)(mi * 16 + l16) * DMODEL + kk * 32 + quad * 8;
                f32x4 a = *(const f32x4*)(p);
                f32x4 b = *(const f32x4*)(p + 4);
                short8 v;
                v[0] = f2bf(a[0]); v[1] = f2bf(a[1]); v[2] = f2bf(a[2]); v[3] = f2bf(a[3]);
                v[4] = f2bf(b[0]); v[5] = f2bf(b[1]); v[6] = f2bf(b[2]); v[7] = f2bf(b[3]);
                xf[mi][kk] = v;
            }
    }

    f32x4 acc2[4][4];  // [di][mi], persistent across chunks
    for (int di = 0; di < 4; ++di)
        for (int mi = 0; mi < 4; ++mi)
            acc2[di][mi] = (f32x4){0.f, 0.f, 0.f, 0.f};

    const short* s1 = w1t + (size_t)h * NFF * DHEAD;
    const short* s2 = w2t + (size_t)h * DHEAD * NFF;

    for (int c = 0; c < 4; ++c) {
        // ---- stage W1 chunk (contiguous 32KB bf16) and W2 chunk (128 rows, stride NFF)
        for (int p = 0; p < 8; ++p) {
            int v = p * 256 + tid;          // 0..2047
            int r = v >> 4;                 // 0..127
            int cc = (v & 15) * 8;          // 0..120
            *(short8*)&W1s[r][cc] = *(const short8*)(s1 + (size_t)(c * FC + r) * DHEAD + cc);
            *(short8*)&W2s[r][cc] = *(const short8*)(s2 + (size_t)r * NFF + c * FC + cc);
        }
        __syncthreads();

        // ---- GEMM1: acc1[fi][mi] over k=d (4 steps of 32)
        f32x4 acc1[4][4];
        for (int fi = 0; fi < 4; ++fi)
            for (int mi = 0; mi < 4; ++mi)
                acc1[fi][mi] = (f32x4){0.f, 0.f, 0.f, 0.f};
        for (int kk = 0; kk < 4; ++kk) {
            short8 af[4];
            for (int fi = 0; fi < 4; ++fi)
                af[fi] = *(const short8*)&W1s[wf * 64 + fi * 16 + l16][kk * 32 + quad * 8];
            for (int fi = 0; fi < 4; ++fi)
                for (int mi = 0; mi < 4; ++mi)
                    acc1[fi][mi] = __builtin_amdgcn_mfma_f32_16x16x32_bf16(
                        af[fi], xf[mi][kk], acc1[fi][mi], 0, 0, 0);
        }

        // ---- bias + relu -> Hs[m][f] bf16 (packed 8B writes: regs = consecutive f rows)
        for (int fi = 0; fi < 4; ++fi) {
            const float* pb = b1 + h * NFF + c * FC + wf * 64 + fi * 16 + quad * 4;
            float bb[4] = {pb[0], pb[1], pb[2], pb[3]};
            for (int mi = 0; mi < 4; ++mi) {
                int m = wm * 64 + mi * 16 + l16;
                short4v hv;
                for (int r = 0; r < 4; ++r)
                    hv[r] = f2bf(fmaxf(acc1[fi][mi][r] + bb[r], 0.f));
                *(short4v*)&Hs[m][wf * 64 + fi * 16 + quad * 4] = hv;
            }
        }
        __syncthreads();

        // ---- GEMM2: acc2[di][mi] += W2T(A) x H(B) over k=f (4 steps of 32)
        for (int kk = 0; kk < 4; ++kk) {
            short8 wfr[4], hfr[4];
            for (int di = 0; di < 4; ++di)
                wfr[di] = *(const short8*)&W2s[wf * 64 + di * 16 + l16][kk * 32 + quad * 8];
            for (int mi = 0; mi < 4; ++mi)
                hfr[mi] = *(const short8*)&Hs[wm * 64 + mi * 16 + l16][kk * 32 + quad * 8];
            for (int di = 0; di < 4; ++di)
                for (int mi = 0; mi < 4; ++mi)
                    acc2[di][mi] = __builtin_amdgcn_mfma_f32_16x16x32_bf16(
                        wfr[di], hfr[mi], acc2[di][mi], 0, 0, 0);
        }
        __syncthreads();  // before next chunk's staging overwrites W1s/W2s/Hs
    }

    // ---- epilogue: out[m0+m][h*128 + d] fp32, packed 16B stores (regs = consecutive d)
    for (int di = 0; di < 4; ++di) {
        const float* pb = b2 + h * DHEAD + wf * 64 + di * 16 + quad * 4;
        float bb[4] = {pb[0], pb[1], pb[2], pb[3]};
        for (int mi = 0; mi < 4; ++mi) {
            int m = m0 + wm * 64 + mi * 16 + l16;
            f32x4 ov;
            for (int r = 0; r < 4; ++r)
                ov[r] = acc2[di][mi][r] + bb[r];
            *(f32x4*)(out + (size_t)m * DMODEL + h * DHEAD + wf * 64 + di * 16 + quad * 4) = ov;
        }
    }
}

extern "C" void kernel_launch(void* const* d_in, const int* in_sizes, int n_in,
                              void* d_out, int out_size, void* d_ws, size_t ws_size,
                              hipStream_t stream) {
    const float* x  = (const float*)d_in[0];
    const float* W1 = (const float*)d_in[1];
    const float* b1 = (const float*)d_in[2];
    const float* W2 = (const float*)d_in[3];
    const float* b2 = (const float*)d_in[4];
    float* out = (float*)d_out;

    short* w1t = (short*)d_ws;                                  // [16][512][128] bf16
    short* w2t = (short*)d_ws + (size_t)NHEADS * NFF * DHEAD;   // [16][128][512] bf16

    // W1 [h][128][512] fp32 -> w1t [h][512][128] bf16
    transpose_k<<<dim3(NFF / 32, DHEAD / 32, NHEADS), 256, 0, stream>>>(W1, w1t, DHEAD, NFF);
    // W2 [h][512][128] fp32 -> w2t [h][128][512] bf16
    transpose_k<<<dim3(DHEAD / 32, NFF / 32, NHEADS), 256, 0, stream>>>(W2, w2t, NFF, DHEAD);

    ffn_main<<<dim3(NHEADS, NTOK / MT), 256, 0, stream>>>(x, w1t, b1, w2t, b2, out);
}